// Round 1
// 784.154 us; speedup vs baseline: 1.1161x; 1.1161x over previous
//
#include <hip/hip_runtime.h>
#include <stdint.h>

#define B 8
#define N 8192
#define NG 512
#define GS 32

typedef unsigned long long ull;
typedef float v2f __attribute__((ext_vector_type(2)));

// Exact (no-FMA, left-to-right) squared distance: ((dx*dx + dy*dy) + dz*dz)
__device__ __forceinline__ float sq3(float dx, float dy, float dz) {
#pragma clang fp contract(off)
  return dx * dx + dy * dy + dz * dz;
}

// ---------------- Kernel 1: SE(3) transform, AoS xyz -> SoA xs/ys/zs ------
__global__ void transform_k(const float* __restrict__ xyz,
                            const float* __restrict__ pose,
                            float* __restrict__ xs, float* __restrict__ ys,
                            float* __restrict__ zs) {
#pragma clang fp contract(off)
  int i = blockIdx.x * blockDim.x + threadIdx.x;
  if (i >= B * N) return;
  int b = i / N;
  const float* P = pose + b * 12;  // (3,4) row-major: R|t
  float p0 = xyz[i * 3 + 0], p1 = xyz[i * 3 + 1], p2 = xyz[i * 3 + 2];
  // exact order: ((r0*p0 + r1*p1) + r2*p2) + t
  float ox = ((P[0] * p0 + P[1] * p1) + P[2] * p2) + P[3];
  float oy = ((P[4] * p0 + P[5] * p1) + P[6] * p2) + P[7];
  float oz = ((P[8] * p0 + P[9] * p1) + P[10] * p2) + P[11];
  xs[i] = ox;
  ys[i] = oy;
  zs[i] = oz;
}

// ---------------- Kernel 2: farthest point sampling, 1 block per batch ----
// 256 threads (4 waves), 16 float2 (=32 points) per thread, ONE barrier/step.
// Points mirrored in LDS so the winner's coords are fetched via LDS (not a
// dependent global load) and broadcast together with the key.
#define FPS_T 256
#define FPS_W (FPS_T / 64)      // 4 waves
#define FPS_J (N / FPS_T / 2)   // 16 float2 per thread

__global__ __launch_bounds__(FPS_T) void fps_k(const float* __restrict__ xs,
                                               const float* __restrict__ ys,
                                               const float* __restrict__ zs,
                                               float* __restrict__ centers) {
#pragma clang fp contract(off)
  int b = blockIdx.x;
  int t = threadIdx.x;

  __shared__ float plx[N];            // LDS mirror of this batch's points (SoA)
  __shared__ float ply[N];
  __shared__ float plz[N];
  __shared__ ull wkey[2][FPS_W];      // double-buffered per-wave winner keys
  __shared__ float4 wxyz[2][FPS_W];   // ... and winner coords

  const float* __restrict__ bx = xs + b * N;
  const float* __restrict__ by = ys + b * N;
  const float* __restrict__ bz = zs + b * N;
  const v2f* __restrict__ bx2 = (const v2f*)bx;
  const v2f* __restrict__ by2 = (const v2f*)by;
  const v2f* __restrict__ bz2 = (const v2f*)bz;

  // point (j, t, e) has global index p = (j*FPS_T + t)*2 + e
  v2f px[FPS_J], py[FPS_J], pz[FPS_J], dist[FPS_J];
#pragma unroll
  for (int j = 0; j < FPS_J; ++j) {
    int q = j * FPS_T + t;
    px[j] = bx2[q];
    py[j] = by2[q];
    pz[j] = bz2[q];
    ((v2f*)plx)[q] = px[j];  // stage LDS mirror
    ((v2f*)ply)[q] = py[j];
    ((v2f*)plz)[q] = pz[j];
    dist[j].x = 1e10f;  // matches jnp.full(..., 1e10, f32)
    dist[j].y = 1e10f;
  }

  // initial "last" point is index 0 (broadcast global load, off critical path)
  float lx = bx[0], ly = by[0], lz = bz[0];
  __syncthreads();  // LDS mirror ready

  for (int k = 0; k < NG; ++k) {
    if (t == 0) {  // emit 'last' BEFORE update (scan output order); posted store
      int o = (b * NG + k) * 3;
      centers[o + 0] = lx;
      centers[o + 1] = ly;
      centers[o + 2] = lz;
    }

    // exact min-update + local max (packed f32: pk ops, same rounding)
    v2f vmax2;
    vmax2.x = -1.0f;
    vmax2.y = -1.0f;
#pragma unroll
    for (int j = 0; j < FPS_J; ++j) {
      v2f dx = px[j] - lx, dy = py[j] - ly, dz = pz[j] - lz;
      v2f d = (dx * dx + dy * dy) + dz * dz;
      v2f dm;
      dm.x = fminf(dist[j].x, d.x);
      dm.y = fminf(dist[j].y, d.y);
      dist[j] = dm;
      vmax2.x = fmaxf(vmax2.x, dm.x);
      vmax2.y = fmaxf(vmax2.y, dm.y);
    }
    float vmax = fmaxf(vmax2.x, vmax2.y);

    // smallest local index achieving vmax (argmax-first semantics)
    int cand = 0x7fffffff;
#pragma unroll
    for (int j = 0; j < FPS_J; ++j) {
      int p = (j * FPS_T + t) * 2;
      cand = min(cand, (dist[j].x == vmax) ? p : 0x7fffffff);
      cand = min(cand, (dist[j].y == vmax) ? (p + 1) : 0x7fffffff);
    }
    // pack: max over key == max dist, tie -> min index
    ull key = ((ull)__float_as_uint(vmax) << 32) | (ull)(unsigned)(N - 1 - cand);
#pragma unroll
    for (int off = 32; off >= 1; off >>= 1) {
      ull o = __shfl_xor(key, off, 64);
      key = (o > key) ? o : key;
    }

    int kb = k & 1;
    if ((t & 63) == 0) {
      // every lane has the wave-max key; decode winner idx, fetch coords from
      // LDS mirror (~120 cyc, overlapped across the 4 waves), publish both.
      int wc = N - 1 - (int)(unsigned)key;
      float cx = plx[wc], cy = ply[wc], cz = plz[wc];
      wkey[kb][t >> 6] = key;
      wxyz[kb][t >> 6] = make_float4(cx, cy, cz, 0.0f);
    }
    __syncthreads();

    // cross-wave serial reduce over 4 partials, selecting coords with the key
    ull gk = wkey[kb][0];
    float4 c0 = wxyz[kb][0];
    float cx = c0.x, cy = c0.y, cz = c0.z;
#pragma unroll
    for (int w = 1; w < FPS_W; ++w) {
      ull o = wkey[kb][w];
      float4 oc = wxyz[kb][w];
      bool sw = o > gk;
      gk = sw ? o : gk;
      cx = sw ? oc.x : cx;
      cy = sw ? oc.y : cy;
      cz = sw ? oc.z : cz;
    }
    lx = cx;
    ly = cy;
    lz = cz;
    // no second barrier: next iter writes wkey/wxyz[(k+1)&1] (other buffer)
  }
}

// ---------------- Kernel 3: exact 32-NN per center, 1 block per center ----
#define KNN_T 256
#define KNN_P (N / KNN_T)  // 32 points per thread

__global__ __launch_bounds__(KNN_T) void knn_k(const float* __restrict__ xs,
                                               const float* __restrict__ ys,
                                               const float* __restrict__ zs,
                                               const float* __restrict__ centers,
                                               float* __restrict__ out) {
#pragma clang fp contract(off)
  int b = blockIdx.y, g = blockIdx.x, t = threadIdx.x;
  const float* bx = xs + b * N;
  const float* by = ys + b * N;
  const float* bz = zs + b * N;
  int ci = (b * NG + g) * 3;
  float cx = centers[ci], cy = centers[ci + 1], cz = centers[ci + 2];

  // packed keys: (distBits<<32)|idx ; min over key == min dist, tie -> min idx
  ull key[KNN_P];
  ull lmin = ~0ull;
#pragma unroll
  for (int j = 0; j < KNN_P; ++j) {
    int p = j * KNN_T + t;
    float dx = bx[p] - cx, dy = by[p] - cy, dz = bz[p] - cz;
    float d = sq3(dx, dy, dz);
    key[j] = ((ull)__float_as_uint(d) << 32) | (ull)(unsigned)p;
    lmin = (key[j] < lmin) ? key[j] : lmin;
  }

  __shared__ ull wred[KNN_T / 64];
  __shared__ int widx[GS];

  for (int k = 0; k < GS; ++k) {
    ull v = lmin;
#pragma unroll
    for (int off = 32; off >= 1; off >>= 1) {
      ull o = __shfl_xor(v, off, 64);
      v = (o < v) ? o : v;
    }
    if ((t & 63) == 0) wred[t >> 6] = v;
    __syncthreads();

    ull gm = wred[0];
#pragma unroll
    for (int w = 1; w < KNN_T / 64; ++w) {
      ull o = wred[w];
      gm = (o < gm) ? o : gm;
    }
    int idx = (int)(unsigned)gm;

    // only the owning lane rescans its keys (cached local min elsewhere)
    if (t == (idx & (KNN_T - 1))) {
      int jj = idx / KNN_T;
#pragma unroll
      for (int j = 0; j < KNN_P; ++j)
        if (j == jj) key[j] = ~0ull;
      lmin = ~0ull;
#pragma unroll
      for (int j = 0; j < KNN_P; ++j) lmin = (key[j] < lmin) ? key[j] : lmin;
    }
    if (t == 0) widx[k] = idx;
    __syncthreads();
  }

  // gather & write neighborhood (B, NG, GS, 3), k ascending by (d, idx)
  if (t < GS) {
    int idx = widx[t];
    int o = ((b * NG + g) * GS + t) * 3;
    out[o + 0] = bx[idx];
    out[o + 1] = by[idx];
    out[o + 2] = bz[idx];
  }
}

extern "C" void kernel_launch(void* const* d_in, const int* in_sizes, int n_in,
                              void* d_out, int out_size, void* d_ws, size_t ws_size,
                              hipStream_t stream) {
  const float* xyz = (const float*)d_in[0];   // (B, N, 3) f32
  const float* pose = (const float*)d_in[1];  // (B, 3, 4) f32
  float* out = (float*)d_out;                 // neighborhood (B,NG,GS,3) ++ center (B,NG,3)

  float* xs = (float*)d_ws;       // SoA transformed points
  float* ys = xs + B * N;
  float* zs = ys + B * N;
  float* centers = out + B * NG * GS * 3;  // center block of d_out

  transform_k<<<dim3((B * N + 255) / 256), dim3(256), 0, stream>>>(xyz, pose, xs, ys, zs);
  fps_k<<<dim3(B), dim3(FPS_T), 0, stream>>>(xs, ys, zs, centers);
  knn_k<<<dim3(NG, B), dim3(KNN_T), 0, stream>>>(xs, ys, zs, centers, out);
}

// Round 2
// 728.709 us; speedup vs baseline: 1.2010x; 1.0761x over previous
//
#include <hip/hip_runtime.h>
#include <stdint.h>

#define B 8
#define N 8192
#define NG 512
#define GS 32

typedef unsigned long long ull;
typedef float v2f __attribute__((ext_vector_type(2)));

// Exact (no-FMA, left-to-right) squared distance: ((dx*dx + dy*dy) + dz*dz)
__device__ __forceinline__ float sq3(float dx, float dy, float dz) {
#pragma clang fp contract(off)
  return dx * dx + dy * dy + dz * dz;
}

// 64-bit max via DPP move (pure VALU, no LDS pipe). Invalid lanes keep old.
template <int CTRL>
__device__ __forceinline__ ull dpp_max64(ull key) {
  unsigned lo = (unsigned)key, hi = (unsigned)(key >> 32);
  unsigned olo = (unsigned)__builtin_amdgcn_update_dpp((int)lo, (int)lo, CTRL, 0xf, 0xf, false);
  unsigned ohi = (unsigned)__builtin_amdgcn_update_dpp((int)hi, (int)hi, CTRL, 0xf, 0xf, false);
  ull o = ((ull)ohi << 32) | olo;
  return (o > key) ? o : key;
}

// ---------------- Kernel 1: SE(3) transform, AoS xyz -> SoA xs/ys/zs ------
__global__ void transform_k(const float* __restrict__ xyz,
                            const float* __restrict__ pose,
                            float* __restrict__ xs, float* __restrict__ ys,
                            float* __restrict__ zs) {
#pragma clang fp contract(off)
  int i = blockIdx.x * blockDim.x + threadIdx.x;
  if (i >= B * N) return;
  int b = i / N;
  const float* P = pose + b * 12;  // (3,4) row-major: R|t
  float p0 = xyz[i * 3 + 0], p1 = xyz[i * 3 + 1], p2 = xyz[i * 3 + 2];
  // exact order: ((r0*p0 + r1*p1) + r2*p2) + t
  float ox = ((P[0] * p0 + P[1] * p1) + P[2] * p2) + P[3];
  float oy = ((P[4] * p0 + P[5] * p1) + P[6] * p2) + P[7];
  float oz = ((P[8] * p0 + P[9] * p1) + P[10] * p2) + P[11];
  xs[i] = ox;
  ys[i] = oy;
  zs[i] = oz;
}

// ---------------- Kernel 2: farthest point sampling, 1 block per batch ----
// 256 threads (4 waves), 16 float2 (=32 points) per thread, ONE barrier/step.
// Fused update+argmax single pass; DPP (VALU) wave reduction; LDS point
// mirror so the winner's coords never touch global memory.
#define FPS_T 256
#define FPS_W (FPS_T / 64)      // 4 waves
#define FPS_J (N / FPS_T / 2)   // 16 float2 per thread

__global__ __launch_bounds__(FPS_T) void fps_k(const float* __restrict__ xs,
                                               const float* __restrict__ ys,
                                               const float* __restrict__ zs,
                                               float* __restrict__ centers) {
#pragma clang fp contract(off)
  int b = blockIdx.x;
  int t = threadIdx.x;

  __shared__ float plx[N];            // LDS mirror of this batch's points (SoA)
  __shared__ float ply[N];
  __shared__ float plz[N];
  __shared__ ull wkey[2][FPS_W];      // double-buffered per-wave winner keys
  __shared__ float4 wxyz[2][FPS_W];   // ... and winner coords

  const float* __restrict__ bx = xs + b * N;
  const float* __restrict__ by = ys + b * N;
  const float* __restrict__ bz = zs + b * N;
  const v2f* __restrict__ bx2 = (const v2f*)bx;
  const v2f* __restrict__ by2 = (const v2f*)by;
  const v2f* __restrict__ bz2 = (const v2f*)bz;

  // point (j, t, e) has global index p = (j*FPS_T + t)*2 + e
  v2f px[FPS_J], py[FPS_J], pz[FPS_J], dist[FPS_J];
#pragma unroll
  for (int j = 0; j < FPS_J; ++j) {
    int q = j * FPS_T + t;
    px[j] = bx2[q];
    py[j] = by2[q];
    pz[j] = bz2[q];
    ((v2f*)plx)[q] = px[j];  // stage LDS mirror
    ((v2f*)ply)[q] = py[j];
    ((v2f*)plz)[q] = pz[j];
    dist[j].x = 1e10f;  // matches jnp.full(..., 1e10, f32)
    dist[j].y = 1e10f;
  }

  // initial "last" point is index 0 (broadcast global load, off critical path)
  float lx = bx[0], ly = by[0], lz = bz[0];
  __syncthreads();  // LDS mirror ready

  for (int k = 0; k < NG; ++k) {
    if (t == 0) {  // emit 'last' BEFORE update (scan output order); posted store
      int o = (b * NG + k) * 3;
      centers[o + 0] = lx;
      centers[o + 1] = ly;
      centers[o + 2] = lz;
    }

    // Fused exact min-update + first-occurrence argmax.
    // 4 independent (best,code) accumulators keep the cndmask chain short.
    // code = j*2+e  (within-thread idx order ascending => strict '>' keeps
    // the first occurrence inside each accumulator's subsequence).
    float bd0 = -1.0f, bd1 = -1.0f, bd2 = -1.0f, bd3 = -1.0f;
    int bc0 = 0, bc1 = 0, bc2 = 0, bc3 = 0;
#pragma unroll
    for (int j = 0; j < FPS_J; ++j) {
      v2f dx = px[j] - lx, dy = py[j] - ly, dz = pz[j] - lz;
      v2f d = (dx * dx + dy * dy) + dz * dz;
      v2f dm;
      dm.x = fminf(dist[j].x, d.x);
      dm.y = fminf(dist[j].y, d.y);
      dist[j] = dm;
      int a = j & 3;
      float* bdp = (a == 0) ? &bd0 : (a == 1) ? &bd1 : (a == 2) ? &bd2 : &bd3;
      int* bcp = (a == 0) ? &bc0 : (a == 1) ? &bc1 : (a == 2) ? &bc2 : &bc3;
      bool g0 = dm.x > *bdp;
      *bdp = g0 ? dm.x : *bdp;
      *bcp = g0 ? (2 * j) : *bcp;
      bool g1 = dm.y > *bdp;
      *bdp = g1 ? dm.y : *bdp;
      *bcp = g1 ? (2 * j + 1) : *bcp;
    }
    // tie-aware merges: equal dist -> smaller code (codes are in idx order)
    {
      bool s1 = (bd1 > bd0) || ((bd1 == bd0) && (bc1 < bc0));
      bd0 = s1 ? bd1 : bd0; bc0 = s1 ? bc1 : bc0;
      bool s2 = (bd3 > bd2) || ((bd3 == bd2) && (bc3 < bc2));
      bd2 = s2 ? bd3 : bd2; bc2 = s2 ? bc3 : bc2;
      bool s3 = (bd2 > bd0) || ((bd2 == bd0) && (bc2 < bc0));
      bd0 = s3 ? bd2 : bd0; bc0 = s3 ? bc2 : bc0;
    }
    // reconstruct global point index: idx = (j*FPS_T + t)*2 + e
    int cand = (bc0 >> 1) * (FPS_T * 2) + t * 2 + (bc0 & 1);
    // pack: max over key == max dist, tie -> min index
    ull key = ((ull)__float_as_uint(bd0) << 32) | (ull)(unsigned)(N - 1 - cand);

    // wave-level max via DPP (VALU only): row_shr 1/2/4/8, bcast 15/31
    key = dpp_max64<0x111>(key);
    key = dpp_max64<0x112>(key);
    key = dpp_max64<0x114>(key);
    key = dpp_max64<0x118>(key);
    key = dpp_max64<0x142>(key);
    key = dpp_max64<0x143>(key);
    // lane 63 holds the wave max; broadcast via readlane (uniform SGPR)
    unsigned klo = (unsigned)__builtin_amdgcn_readlane((int)(unsigned)key, 63);
    unsigned khi = (unsigned)__builtin_amdgcn_readlane((int)(unsigned)(key >> 32), 63);
    ull wk = ((ull)khi << 32) | klo;

    int kb = k & 1;
    if ((t & 63) == 0) {
      // decode wave winner, fetch coords from LDS mirror (pre-barrier overlap)
      int wc = (N - 1) - (int)(unsigned)(wk & 0xffffffffu);
      wkey[kb][t >> 6] = wk;
      wxyz[kb][t >> 6] = make_float4(plx[wc], ply[wc], plz[wc], 0.0f);
    }
    __syncthreads();

    // cross-wave serial reduce over 4 partials, selecting coords with the key
    ull gk = wkey[kb][0];
    float4 c0 = wxyz[kb][0];
    float cx = c0.x, cy = c0.y, cz = c0.z;
#pragma unroll
    for (int w = 1; w < FPS_W; ++w) {
      ull o = wkey[kb][w];
      float4 oc = wxyz[kb][w];
      bool sw = o > gk;
      gk = sw ? o : gk;
      cx = sw ? oc.x : cx;
      cy = sw ? oc.y : cy;
      cz = sw ? oc.z : cz;
    }
    lx = cx;
    ly = cy;
    lz = cz;
    // no second barrier: next iter writes wkey/wxyz[(k+1)&1] (other buffer)
  }
}

// ---------------- Kernel 3: exact 32-NN per center, 1 block per center ----
#define KNN_T 256
#define KNN_P (N / KNN_T)  // 32 points per thread

__global__ __launch_bounds__(KNN_T) void knn_k(const float* __restrict__ xs,
                                               const float* __restrict__ ys,
                                               const float* __restrict__ zs,
                                               const float* __restrict__ centers,
                                               float* __restrict__ out) {
#pragma clang fp contract(off)
  int b = blockIdx.y, g = blockIdx.x, t = threadIdx.x;
  const float* bx = xs + b * N;
  const float* by = ys + b * N;
  const float* bz = zs + b * N;
  int ci = (b * NG + g) * 3;
  float cx = centers[ci], cy = centers[ci + 1], cz = centers[ci + 2];

  // packed keys: (distBits<<32)|idx ; min over key == min dist, tie -> min idx
  ull key[KNN_P];
  ull lmin = ~0ull;
#pragma unroll
  for (int j = 0; j < KNN_P; ++j) {
    int p = j * KNN_T + t;
    float dx = bx[p] - cx, dy = by[p] - cy, dz = bz[p] - cz;
    float d = sq3(dx, dy, dz);
    key[j] = ((ull)__float_as_uint(d) << 32) | (ull)(unsigned)p;
    lmin = (key[j] < lmin) ? key[j] : lmin;
  }

  __shared__ ull wred[KNN_T / 64];
  __shared__ int widx[GS];

  for (int k = 0; k < GS; ++k) {
    ull v = lmin;
#pragma unroll
    for (int off = 32; off >= 1; off >>= 1) {
      ull o = __shfl_xor(v, off, 64);
      v = (o < v) ? o : v;
    }
    if ((t & 63) == 0) wred[t >> 6] = v;
    __syncthreads();

    ull gm = wred[0];
#pragma unroll
    for (int w = 1; w < KNN_T / 64; ++w) {
      ull o = wred[w];
      gm = (o < gm) ? o : gm;
    }
    int idx = (int)(unsigned)gm;

    // only the owning lane rescans its keys (cached local min elsewhere)
    if (t == (idx & (KNN_T - 1))) {
      int jj = idx / KNN_T;
#pragma unroll
      for (int j = 0; j < KNN_P; ++j)
        if (j == jj) key[j] = ~0ull;
      lmin = ~0ull;
#pragma unroll
      for (int j = 0; j < KNN_P; ++j) lmin = (key[j] < lmin) ? key[j] : lmin;
    }
    if (t == 0) widx[k] = idx;
    __syncthreads();
  }

  // gather & write neighborhood (B, NG, GS, 3), k ascending by (d, idx)
  if (t < GS) {
    int idx = widx[t];
    int o = ((b * NG + g) * GS + t) * 3;
    out[o + 0] = bx[idx];
    out[o + 1] = by[idx];
    out[o + 2] = bz[idx];
  }
}

extern "C" void kernel_launch(void* const* d_in, const int* in_sizes, int n_in,
                              void* d_out, int out_size, void* d_ws, size_t ws_size,
                              hipStream_t stream) {
  const float* xyz = (const float*)d_in[0];   // (B, N, 3) f32
  const float* pose = (const float*)d_in[1];  // (B, 3, 4) f32
  float* out = (float*)d_out;                 // neighborhood (B,NG,GS,3) ++ center (B,NG,3)

  float* xs = (float*)d_ws;       // SoA transformed points
  float* ys = xs + B * N;
  float* zs = ys + B * N;
  float* centers = out + B * NG * GS * 3;  // center block of d_out

  transform_k<<<dim3((B * N + 255) / 256), dim3(256), 0, stream>>>(xyz, pose, xs, ys, zs);
  fps_k<<<dim3(B), dim3(FPS_T), 0, stream>>>(xs, ys, zs, centers);
  knn_k<<<dim3(NG, B), dim3(KNN_T), 0, stream>>>(xs, ys, zs, centers, out);
}